// Round 1
// baseline (305.776 us; speedup 1.0000x reference)
//
#include <hip/hip_runtime.h>
#include <hip/hip_bf16.h>
#include <math.h>

#define L 2048
#define DM 1024
#define ED 2048
#define NST 16
#define DTR 64
#define BETA 0.6f
#define NCHUNK 64
#define LCH 32            // L / NCHUNK
#define SPLITS 16         // GEMM2 split-K
#define SPLIT4 4          // GEMM4 split-K

typedef __bf16 bf16_t;
typedef __bf16 bf16x8 __attribute__((ext_vector_type(8)));
typedef __bf16 bf16x4 __attribute__((ext_vector_type(4)));
typedef float  floatx4 __attribute__((ext_vector_type(4)));

// ---------------- utility kernels ----------------

__global__ void k_fill(float* __restrict__ p, float v, int n) {
    int i = blockIdx.x * 256 + threadIdx.x;
    if (i < n) p[i] = v;
}

// merged f32->bf16 conversion for all 5 constant-ish inputs.
// Segment boundaries (in float4 units) are all multiples of 256, so every
// wave takes exactly one branch (no divergence) and grid covers total exactly.
//  x:     524288   cum  524288
//  W_in: 1048576   cum 1572864
//  W_x:    49152   cum 1622016
//  W_dt:   32768   cum 1654784
//  W_out: 524288   cum 2179072  = 8512 blocks * 256
__global__ void k_cvt_all(const float4* __restrict__ s0, bf16x4* __restrict__ d0,
                          const float4* __restrict__ s1, bf16x4* __restrict__ d1,
                          const float4* __restrict__ s2, bf16x4* __restrict__ d2,
                          const float4* __restrict__ s3, bf16x4* __restrict__ d3,
                          const float4* __restrict__ s4, bf16x4* __restrict__ d4) {
    int i = blockIdx.x * 256 + threadIdx.x;
    const float4* s; bf16x4* d; int j;
    if (i < 524288)        { s = s0; d = d0; j = i; }
    else if (i < 1572864)  { s = s1; d = d1; j = i - 524288; }
    else if (i < 1622016)  { s = s2; d = d2; j = i - 1572864; }
    else if (i < 1654784)  { s = s3; d = d3; j = i - 1622016; }
    else                   { s = s4; d = d4; j = i - 1654784; }
    float4 f = s[j];
    bf16x4 o;
    o[0] = (bf16_t)f.x; o[1] = (bf16_t)f.y; o[2] = (bf16_t)f.z; o[3] = (bf16_t)f.w;
    d[j] = o;
}

// ---------------- bf16 GEMM-BT:  C(M,N) = X(M,K) @ W(N,K)^T ----------------
// GUARD=false: N%128==0, uses global_load_lds width-16 staging (m97 pattern).
// GUARD=true : ragged N (zero-fill B rows >= N, guarded stores), VGPR staging.
// blockIdx.z = split-K index: k range [z*ksz, z*ksz+ksz), C += z*M*ldc elems.
// EPI 0: plain f32 store. EPI 1: softplus(v + bias[col]) -> bf16 store.
// EPI 2: plain bf16 store (C reinterpreted as bf16_t*).
template<int EPI, bool GUARD>
__global__ __launch_bounds__(256)
void k_gemm_bt(const bf16_t* __restrict__ X, const bf16_t* __restrict__ W,
               float* __restrict__ C, int M, int N, int K, int ldc, int ksz,
               const float* __restrict__ bias) {
    __shared__ bf16_t As[128 * 32];
    __shared__ bf16_t Bs[128 * 32];
    const int tid  = threadIdx.x;
    const int bx   = blockIdx.x, by = blockIdx.y;
    const int kbase = blockIdx.z * ksz;
    const size_t zoff = (size_t)blockIdx.z * M * ldc;
    const int wave = tid >> 6, lane = tid & 63;
    const int wm   = (wave >> 1) * 64;
    const int wn   = (wave & 1) * 64;
    const int quad = lane >> 4, l16 = lane & 15;

    floatx4 acc[4][4];
#pragma unroll
    for (int i = 0; i < 4; i++)
#pragma unroll
        for (int j = 0; j < 4; j++)
            acc[i][j] = (floatx4){0.f, 0.f, 0.f, 0.f};

    for (int kt = kbase; kt < kbase + ksz; kt += 32) {
        if (GUARD) {
#pragma unroll
            for (int p = 0; p < 2; p++) {
                int e = p * 2048 + tid * 8;
                int r = e >> 5, c = e & 31;
                int arow = by * 128 + r;
                *(float4*)(&As[r * 32 + c]) =
                    *(const float4*)(&X[(size_t)arow * K + kt + c]);
                int brow = bx * 128 + r;
                float4 bv = make_float4(0.f, 0.f, 0.f, 0.f);
                if (brow < N) bv = *(const float4*)(&W[(size_t)brow * K + kt + c]);
                *(float4*)(&Bs[r * 32 + c]) = bv;
            }
        } else {
            // async global->LDS, 16B/lane; LDS dest = wave-uniform base + lane*16
#pragma unroll
            for (int p = 0; p < 2; p++) {
                int e = p * 2048 + tid * 8;     // bf16 elem idx; byte off = p*4096 + tid*16
                int r = e >> 5, c = e & 31;
                __builtin_amdgcn_global_load_lds(
                    (const __attribute__((address_space(1))) void*)&X[(size_t)(by * 128 + r) * K + kt + c],
                    (__attribute__((address_space(3))) void*)&As[e], 16, 0, 0);
                __builtin_amdgcn_global_load_lds(
                    (const __attribute__((address_space(1))) void*)&W[(size_t)(bx * 128 + r) * K + kt + c],
                    (__attribute__((address_space(3))) void*)&Bs[e], 16, 0, 0);
            }
        }
        __syncthreads();

        bf16x8 af[4], bfr[4];
#pragma unroll
        for (int mt = 0; mt < 4; mt++)
            af[mt] = *(const bf16x8*)(&As[(wm + mt * 16 + l16) * 32 + quad * 8]);
#pragma unroll
        for (int nt = 0; nt < 4; nt++)
            bfr[nt] = *(const bf16x8*)(&Bs[(wn + nt * 16 + l16) * 32 + quad * 8]);
#pragma unroll
        for (int mt = 0; mt < 4; mt++)
#pragma unroll
            for (int nt = 0; nt < 4; nt++)
                acc[mt][nt] = __builtin_amdgcn_mfma_f32_16x16x32_bf16(
                    af[mt], bfr[nt], acc[mt][nt], 0, 0, 0);
        __syncthreads();
    }

    // epilogue: D layout col = lane&15, row = quad*4 + reg
#pragma unroll
    for (int mt = 0; mt < 4; mt++) {
#pragma unroll
        for (int nt = 0; nt < 4; nt++) {
            int col = bx * 128 + wn + nt * 16 + l16;
            if (!GUARD || col < N) {
#pragma unroll
                for (int r4 = 0; r4 < 4; r4++) {
                    int row = by * 128 + wm + mt * 16 + quad * 4 + r4;
                    float v = acc[mt][nt][r4];
                    size_t off = zoff + (size_t)row * ldc + col;
                    if (EPI == 0) {
                        C[off] = v;
                    } else if (EPI == 1) {
                        v += bias[col];
                        v = (v > 20.f) ? v : log1pf(__expf(v));
                        ((bf16_t*)C)[off] = (bf16_t)v;
                    } else {
                        ((bf16_t*)C)[off] = (bf16_t)v;
                    }
                }
            }
        }
    }
}

// reduce GEMM4 bf16 split-K partials -> f32 out. 8 elems/thread.
__global__ void k_red4(const bf16x8* __restrict__ part, float4* __restrict__ out) {
    int i = blockIdx.x * 256 + threadIdx.x;     // L*DM/8 threads
    const int stride = L * DM / 8;
    bf16x8 a = part[i], b = part[i + stride];
    bf16x8 c = part[i + 2 * stride], d = part[i + 3 * stride];
    float4 o0, o1;
    o0.x = (float)a[0] + (float)b[0] + (float)c[0] + (float)d[0];
    o0.y = (float)a[1] + (float)b[1] + (float)c[1] + (float)d[1];
    o0.z = (float)a[2] + (float)b[2] + (float)c[2] + (float)d[2];
    o0.w = (float)a[3] + (float)b[3] + (float)c[3] + (float)d[3];
    o1.x = (float)a[4] + (float)b[4] + (float)c[4] + (float)d[4];
    o1.y = (float)a[5] + (float)b[5] + (float)c[5] + (float)d[5];
    o1.z = (float)a[6] + (float)b[6] + (float)c[6] + (float)d[6];
    o1.w = (float)a[7] + (float)b[7] + (float)c[7] + (float)d[7];
    out[2 * i]     = o0;
    out[2 * i + 1] = o1;
}

// ---------------- depthwise causal conv (K=4) + silu ----------------
// xz now bf16; accumulate in f32; emit only bf16 (scan reads bf16 too).
__global__ void k_conv_silu(const bf16_t* __restrict__ xz,
                            const float* __restrict__ conv_w,
                            const float* __restrict__ conv_b,
                            bf16_t* __restrict__ xc_bf) {
    int idx = blockIdx.x * 256 + threadIdx.x;   // over L*ED
    int e = idx & (ED - 1);
    int t = idx >> 11;
    float w0 = conv_w[e * 4 + 0], w1 = conv_w[e * 4 + 1];
    float w2 = conv_w[e * 4 + 2], w3 = conv_w[e * 4 + 3];
    const bf16_t* col = xz + e;
    float acc = conv_b[e];
    if (t >= 3) acc += w0 * (float)col[(size_t)(t - 3) * 4096];
    if (t >= 2) acc += w1 * (float)col[(size_t)(t - 2) * 4096];
    if (t >= 1) acc += w2 * (float)col[(size_t)(t - 1) * 4096];
    acc += w3 * (float)col[(size_t)t * 4096];
    float s = acc / (1.f + __expf(-acc));       // silu
    xc_bf[idx] = (bf16_t)s;
}

// reduce GEMM2 split-K partials -> dBC fp32; also emit dly bf16 (cols 0:64)
__global__ void k_red2(const float* __restrict__ part, float* __restrict__ dBC,
                       bf16_t* __restrict__ dly) {
    int idx = blockIdx.x * 256 + threadIdx.x;   // L*96
    int t = idx / 96, c = idx - t * 96;
    float s = 0.f;
#pragma unroll
    for (int sp = 0; sp < SPLITS; sp++) s += part[(size_t)sp * L * 96 + idx];
    dBC[idx] = s;
    if (c < 64) dly[t * 64 + c] = (bf16_t)s;
}

// ---------------- chunked scan: thread = (chunk, e), 16 n-states in regs ----
// recurrence per (e,n):  v_t = B*v_{t-1} + u_t ;  h_t = a_t*h_{t-1} + v_t
// pass1 computes transition summary (h,v,p,q) per chunk with zero init;
// combine turns summaries into incoming states, written to compact float2 inc
// (p2 only needs 8B/state; reading .xy out of float4 fetched full lines);
// pass2 re-runs the recurrence from the true incoming state and emits gated g.
// summ layout: [n][chunk][e] float4 -> coalesced per-instr access everywhere.

__global__ __launch_bounds__(256)
void k_scan_p1(const bf16_t* __restrict__ delta, const bf16_t* __restrict__ xc,
               const float* __restrict__ dBC, const float* __restrict__ A_log,
               float4* __restrict__ summ) {
    const int chunk = blockIdx.x >> 3;                 // 8 blocks per chunk
    const int e = (blockIdx.x & 7) * 256 + threadIdx.x;
    float A[NST];
#pragma unroll
    for (int n = 0; n < NST; n++) A[n] = -__expf(A_log[e * NST + n]);
    float h[NST], v[NST], p[NST], q[NST];
#pragma unroll
    for (int n = 0; n < NST; n++) { h[n] = 0.f; v[n] = 0.f; p[n] = 1.f; q[n] = 0.f; }
    float bp = 1.f;
    const int t0 = chunk * LCH;
    for (int i = 0; i < LCH; i++) {
        int t = t0 + i;                                // block-uniform
        float d   = (float)delta[(size_t)t * ED + e];
        float xcv = (float)xc[(size_t)t * ED + e];
        float du  = d * xcv;
        bp *= BETA;
        const float* Bp = &dBC[t * 96 + 64];           // wave-uniform -> scalar loads
#pragma unroll
        for (int n = 0; n < NST; n++) {
            float a = __expf(d * A[n]);
            v[n] = BETA * v[n] + du * Bp[n];
            h[n] = a * h[n] + v[n];
            p[n] *= a;
            q[n] = a * q[n] + bp;
        }
    }
#pragma unroll
    for (int n = 0; n < NST; n++)
        summ[((size_t)n * NCHUNK + chunk) * ED + e] = make_float4(h[n], v[n], p[n], q[n]);
}

// sequential over chunks; writes incoming state (h,v) to compact inc array
__global__ void k_combine(const float4* __restrict__ summ, float2* __restrict__ inc) {
    int tid = blockIdx.x * 256 + threadIdx.x;   // ED*NST threads; tid = n*ED + e
    int n = tid >> 11, e = tid & (ED - 1);
    float h = 0.f, v = 0.f;
    const float bl = 7.9586611e-8f;             // 0.6^32
#pragma unroll 4
    for (int c = 0; c < NCHUNK; c++) {
        size_t idx = ((size_t)n * NCHUNK + c) * ED + e;
        float4 f = summ[idx];                   // (hL, vL, p, q)
        inc[idx] = make_float2(h, v);           // incoming state for chunk c
        float hn = f.z * h + f.w * v + f.x;
        v = bl * v + f.y;
        h = hn;
    }
}

__global__ __launch_bounds__(256)
void k_scan_p2(const bf16_t* __restrict__ delta, const bf16_t* __restrict__ xc,
               const float* __restrict__ dBC, const float* __restrict__ A_log,
               const float2* __restrict__ inc, const float* __restrict__ Dvec,
               const bf16_t* __restrict__ xz, bf16_t* __restrict__ g) {
    const int chunk = blockIdx.x >> 3;
    const int e = (blockIdx.x & 7) * 256 + threadIdx.x;
    float A[NST];
#pragma unroll
    for (int n = 0; n < NST; n++) A[n] = -__expf(A_log[e * NST + n]);
    float h[NST], v[NST];
#pragma unroll
    for (int n = 0; n < NST; n++) {
        float2 s = inc[((size_t)n * NCHUNK + chunk) * ED + e];
        h[n] = s.x; v[n] = s.y;                 // true incoming state: no p/q needed
    }
    const float De = Dvec[e];
    const int t0 = chunk * LCH;
    for (int i = 0; i < LCH; i++) {
        int t = t0 + i;
        float d   = (float)delta[(size_t)t * ED + e];
        float xcv = (float)xc[(size_t)t * ED + e];
        float du  = d * xcv;
        const float* Bp = &dBC[t * 96 + 64];
        const float* Cp = &dBC[t * 96 + 80];
        float yacc = 0.f;
#pragma unroll
        for (int n = 0; n < NST; n++) {
            float a = __expf(d * A[n]);
            v[n] = BETA * v[n] + du * Bp[n];
            h[n] = a * h[n] + v[n];
            yacc += Cp[n] * h[n];
        }
        // fused gate: g = bf16((y + D*xc) * silu(z)); z from bf16 xz
        float z = (float)xz[(size_t)t * 4096 + ED + e];
        float sz = z / (1.f + __expf(-z));
        g[(size_t)t * ED + e] = (bf16_t)((yacc + De * xcv) * sz);
    }
}

// ---------------- launch ----------------

extern "C" void kernel_launch(void* const* d_in, const int* in_sizes, int n_in,
                              void* d_out, int out_size, void* d_ws, size_t ws_size,
                              hipStream_t stream) {
    const float* x      = (const float*)d_in[0];
    const float* W_in   = (const float*)d_in[1];
    const float* conv_w = (const float*)d_in[2];
    const float* conv_b = (const float*)d_in[3];
    const float* W_x    = (const float*)d_in[4];
    const float* W_dt   = (const float*)d_in[5];
    const float* b_dt   = (const float*)d_in[6];
    const float* A_log  = (const float*)d_in[7];
    const float* Dv     = (const float*)d_in[8];
    const float* W_out  = (const float*)d_in[9];
    float* out = (float*)d_out;

    // workspace layout (bytes); lifetime-based aliasing:
    //  XZ region: xz bf16 (GEMM1..p2, 16MB) then GEMM4 bf16 split-K partials (16MB)
    //  XC region: inc float2 (combine->p2), exactly 16MB
    //  C  region: xc_bf (conv..p2)
    //  DELTA region: delta bf16 (8MB) | g_bf at +8MB (p2..GEMM4)
    //  R1 region: Win_bf | part2 at +16MB | summ alias (33.5MB, after GEMM3)
    constexpr size_t OFF_XZ    = 0;           // 33554432
    constexpr size_t OFF_XC    = 33554432;    // 16777216  inc (float2, 16MB exact)
    constexpr size_t OFF_C     = 50331648;    //  8388608  xc_bf
    constexpr size_t OFF_DELTA = 58720256;    // 16777216  delta bf16 | g_bf at +8MB
    constexpr size_t OFF_R1    = 75497472;    // 33554432
    constexpr size_t OFF_XBF   = 109051904;   //  4194304  x_bf
    constexpr size_t OFF_DBC   = 113246208;   //   786432  dBC (L,96) f32
    constexpr size_t OFF_DLY   = 114032640;   //   262144  delta_r bf16
    constexpr size_t OFF_WX    = 114294784;   //   393216
    constexpr size_t OFF_WDT   = 114688000;   //   262144
    constexpr size_t OFF_WOUT  = 114950144;   //  4194304  Wout_bf (dedicated)
    constexpr size_t WS_NEED   = 119144448;

    if (ws_size < WS_NEED) {   // loud, diagnosable failure
        k_fill<<<(out_size + 255) / 256, 256, 0, stream>>>(out, 1.0e9f, out_size);
        return;
    }

    char* ws = (char*)d_ws;
    bf16_t* xz_bf = (bf16_t*)(ws + OFF_XZ);
    bf16_t* part4 = (bf16_t*)(ws + OFF_XZ);     // alias: xz dead after p2
    float2* inc   = (float2*)(ws + OFF_XC);
    bf16_t* xc_bf = (bf16_t*)(ws + OFF_C);
    bf16_t* delta_bf = (bf16_t*)(ws + OFF_DELTA);
    bf16_t* g_bf  = (bf16_t*)(ws + OFF_DELTA + 8388608);  // delta dead only after p2; separate slot
    bf16_t* Win_bf  = (bf16_t*)(ws + OFF_R1);
    float*  part2   = (float*)(ws + OFF_R1 + 16777216);
    float4* summ    = (float4*)(ws + OFF_R1);   // alias: Win/part2 dead after GEMM3
    bf16_t* x_bf  = (bf16_t*)(ws + OFF_XBF);
    float*  dBC   = (float*)(ws + OFF_DBC);
    bf16_t* dly   = (bf16_t*)(ws + OFF_DLY);
    bf16_t* Wx_bf  = (bf16_t*)(ws + OFF_WX);
    bf16_t* Wdt_bf = (bf16_t*)(ws + OFF_WDT);
    bf16_t* Wout_bf = (bf16_t*)(ws + OFF_WOUT);

    // single merged conversion (fixed wave-uniform segment boundaries)
    k_cvt_all<<<8512, 256, 0, stream>>>(
        (const float4*)x,     (bf16x4*)x_bf,
        (const float4*)W_in,  (bf16x4*)Win_bf,
        (const float4*)W_x,   (bf16x4*)Wx_bf,
        (const float4*)W_dt,  (bf16x4*)Wdt_bf,
        (const float4*)W_out, (bf16x4*)Wout_bf);

    // GEMM1: xz = x @ W_in^T   (M=L, N=4096, K=DM), bf16 output
    {
        dim3 g(4096 / 128, L / 128, 1);
        k_gemm_bt<2, false><<<g, 256, 0, stream>>>(x_bf, Win_bf, (float*)xz_bf, L, 4096, DM, 4096, DM, nullptr);
    }
    k_conv_silu<<<L * ED / 256, 256, 0, stream>>>(xz_bf, conv_w, conv_b, xc_bf);
    // GEMM2 split-K: part2[z] = xc @ W_x^T over k-range z  (M=L, N=96, K=ED)
    {
        dim3 g(1, L / 128, SPLITS);
        k_gemm_bt<0, true><<<g, 256, 0, stream>>>(xc_bf, Wx_bf, part2, L, 96, ED, 96, ED / SPLITS, nullptr);
    }
    k_red2<<<L * 96 / 256, 256, 0, stream>>>(part2, dBC, dly);
    // GEMM3: delta = softplus(dly @ W_dt^T + b_dt)  (M=L, N=ED, K=64), bf16 output
    {
        dim3 g(ED / 128, L / 128, 1);
        k_gemm_bt<1, false><<<g, 256, 0, stream>>>(dly, Wdt_bf, (float*)delta_bf, L, ED, DTR, ED, DTR, b_dt);
    }
    // chunked scan
    k_scan_p1<<<NCHUNK * 8, 256, 0, stream>>>(delta_bf, xc_bf, dBC, A_log, summ);
    k_combine<<<ED * NST / 256, 256, 0, stream>>>(summ, inc);
    k_scan_p2<<<NCHUNK * 8, 256, 0, stream>>>(delta_bf, xc_bf, dBC, A_log, inc, Dv, xz_bf, g_bf);
    // GEMM4 split-K: part4[z] = g @ W_out^T over k-range z  (M=L, N=DM, K=ED), bf16 partials
    {
        dim3 g(DM / 128, L / 128, SPLIT4);
        k_gemm_bt<2, false><<<g, 256, 0, stream>>>(g_bf, Wout_bf, (float*)part4, L, DM, ED, DM, ED / SPLIT4, nullptr);
    }
    k_red4<<<L * DM / 8 / 256, 256, 0, stream>>>((const bf16x8*)part4, (float4*)out);
}

// Round 2
// 244.992 us; speedup vs baseline: 1.2481x; 1.2481x over previous
//
#include <hip/hip_runtime.h>
#include <hip/hip_bf16.h>
#include <math.h>

#define L 2048
#define DM 1024
#define ED 2048
#define NST 16
#define DTR 64
#define BETA 0.6f
#define NCHUNK 64
#define LCH 32            // L / NCHUNK
#define SPLITS 16         // GEMM2 split-K
#define SPLIT4 4          // GEMM4 split-K

typedef __bf16 bf16_t;
typedef __bf16 bf16x8 __attribute__((ext_vector_type(8)));
typedef __bf16 bf16x4 __attribute__((ext_vector_type(4)));
typedef float  floatx4 __attribute__((ext_vector_type(4)));

// ---------------- utility kernels ----------------

__global__ void k_fill(float* __restrict__ p, float v, int n) {
    int i = blockIdx.x * 256 + threadIdx.x;
    if (i < n) p[i] = v;
}

// merged f32->bf16 conversion for all 5 constant-ish inputs.
// Segment boundaries (in float4 units) are all multiples of 256, so every
// wave takes exactly one branch (no divergence) and grid covers total exactly.
//  x:     524288   cum  524288
//  W_in: 1048576   cum 1572864
//  W_x:    49152   cum 1622016
//  W_dt:   32768   cum 1654784
//  W_out: 524288   cum 2179072  = 8512 blocks * 256
__global__ void k_cvt_all(const float4* __restrict__ s0, bf16x4* __restrict__ d0,
                          const float4* __restrict__ s1, bf16x4* __restrict__ d1,
                          const float4* __restrict__ s2, bf16x4* __restrict__ d2,
                          const float4* __restrict__ s3, bf16x4* __restrict__ d3,
                          const float4* __restrict__ s4, bf16x4* __restrict__ d4) {
    int i = blockIdx.x * 256 + threadIdx.x;
    const float4* s; bf16x4* d; int j;
    if (i < 524288)        { s = s0; d = d0; j = i; }
    else if (i < 1572864)  { s = s1; d = d1; j = i - 524288; }
    else if (i < 1622016)  { s = s2; d = d2; j = i - 1572864; }
    else if (i < 1654784)  { s = s3; d = d3; j = i - 1622016; }
    else                   { s = s4; d = d4; j = i - 1654784; }
    float4 f = s[j];
    bf16x4 o;
    o[0] = (bf16_t)f.x; o[1] = (bf16_t)f.y; o[2] = (bf16_t)f.z; o[3] = (bf16_t)f.w;
    d[j] = o;
}

// ---------------- bf16 GEMM-BT:  C(M,N) = X(M,K) @ W(N,K)^T ----------------
// GUARD=false: N%128==0, uses global_load_lds width-16 staging (m97 pattern).
// GUARD=true : ragged N (zero-fill B rows >= N, guarded stores), VGPR staging.
// blockIdx.z = split-K index: k range [z*ksz, z*ksz+ksz), C += z*M*ldc elems.
// EPI 0: plain f32 store. EPI 1: softplus(v + bias[col]) -> bf16 store.
//   NOTE: EPI 1 uses fully-inline __logf(1+__expf(v)), NOT log1pf. log1pf is a
//   non-inlined libm call; 16 call sites in the unrolled epilogue + 64 live acc
//   VGPRs + bf16 cvt temps caused a scratch-spill storm (119 us, VGPR=76).
// EPI 2: plain bf16 store (C reinterpreted as bf16_t*).
template<int EPI, bool GUARD>
__global__ __launch_bounds__(256)
void k_gemm_bt(const bf16_t* __restrict__ X, const bf16_t* __restrict__ W,
               float* __restrict__ C, int M, int N, int K, int ldc, int ksz,
               const float* __restrict__ bias) {
    __shared__ bf16_t As[128 * 32];
    __shared__ bf16_t Bs[128 * 32];
    const int tid  = threadIdx.x;
    const int bx   = blockIdx.x, by = blockIdx.y;
    const int kbase = blockIdx.z * ksz;
    const size_t zoff = (size_t)blockIdx.z * M * ldc;
    const int wave = tid >> 6, lane = tid & 63;
    const int wm   = (wave >> 1) * 64;
    const int wn   = (wave & 1) * 64;
    const int quad = lane >> 4, l16 = lane & 15;

    floatx4 acc[4][4];
#pragma unroll
    for (int i = 0; i < 4; i++)
#pragma unroll
        for (int j = 0; j < 4; j++)
            acc[i][j] = (floatx4){0.f, 0.f, 0.f, 0.f};

    for (int kt = kbase; kt < kbase + ksz; kt += 32) {
        if (GUARD) {
#pragma unroll
            for (int p = 0; p < 2; p++) {
                int e = p * 2048 + tid * 8;
                int r = e >> 5, c = e & 31;
                int arow = by * 128 + r;
                *(float4*)(&As[r * 32 + c]) =
                    *(const float4*)(&X[(size_t)arow * K + kt + c]);
                int brow = bx * 128 + r;
                float4 bv = make_float4(0.f, 0.f, 0.f, 0.f);
                if (brow < N) bv = *(const float4*)(&W[(size_t)brow * K + kt + c]);
                *(float4*)(&Bs[r * 32 + c]) = bv;
            }
        } else {
            // async global->LDS, 16B/lane; LDS dest = wave-uniform base + lane*16
#pragma unroll
            for (int p = 0; p < 2; p++) {
                int e = p * 2048 + tid * 8;     // bf16 elem idx; byte off = p*4096 + tid*16
                int r = e >> 5, c = e & 31;
                __builtin_amdgcn_global_load_lds(
                    (const __attribute__((address_space(1))) void*)&X[(size_t)(by * 128 + r) * K + kt + c],
                    (__attribute__((address_space(3))) void*)&As[e], 16, 0, 0);
                __builtin_amdgcn_global_load_lds(
                    (const __attribute__((address_space(1))) void*)&W[(size_t)(bx * 128 + r) * K + kt + c],
                    (__attribute__((address_space(3))) void*)&Bs[e], 16, 0, 0);
            }
        }
        __syncthreads();

        bf16x8 af[4], bfr[4];
#pragma unroll
        for (int mt = 0; mt < 4; mt++)
            af[mt] = *(const bf16x8*)(&As[(wm + mt * 16 + l16) * 32 + quad * 8]);
#pragma unroll
        for (int nt = 0; nt < 4; nt++)
            bfr[nt] = *(const bf16x8*)(&Bs[(wn + nt * 16 + l16) * 32 + quad * 8]);
#pragma unroll
        for (int mt = 0; mt < 4; mt++)
#pragma unroll
            for (int nt = 0; nt < 4; nt++)
                acc[mt][nt] = __builtin_amdgcn_mfma_f32_16x16x32_bf16(
                    af[mt], bfr[nt], acc[mt][nt], 0, 0, 0);
        __syncthreads();
    }

    // epilogue: D layout col = lane&15, row = quad*4 + reg
#pragma unroll
    for (int mt = 0; mt < 4; mt++) {
#pragma unroll
        for (int nt = 0; nt < 4; nt++) {
            int col = bx * 128 + wn + nt * 16 + l16;
            if (!GUARD || col < N) {
#pragma unroll
                for (int r4 = 0; r4 < 4; r4++) {
                    int row = by * 128 + wm + mt * 16 + quad * 4 + r4;
                    float v = acc[mt][nt][r4];
                    size_t off = zoff + (size_t)row * ldc + col;
                    if (EPI == 0) {
                        C[off] = v;
                    } else if (EPI == 1) {
                        v += bias[col];
                        // inline softplus: no libm call (see note above)
                        v = (v > 20.f) ? v : __logf(1.f + __expf(v));
                        ((bf16_t*)C)[off] = (bf16_t)v;
                    } else {
                        ((bf16_t*)C)[off] = (bf16_t)v;
                    }
                }
            }
        }
    }
}

// reduce GEMM4 bf16 split-K partials -> f32 out. 8 elems/thread.
__global__ void k_red4(const bf16x8* __restrict__ part, float4* __restrict__ out) {
    int i = blockIdx.x * 256 + threadIdx.x;     // L*DM/8 threads
    const int stride = L * DM / 8;
    bf16x8 a = part[i], b = part[i + stride];
    bf16x8 c = part[i + 2 * stride], d = part[i + 3 * stride];
    float4 o0, o1;
    o0.x = (float)a[0] + (float)b[0] + (float)c[0] + (float)d[0];
    o0.y = (float)a[1] + (float)b[1] + (float)c[1] + (float)d[1];
    o0.z = (float)a[2] + (float)b[2] + (float)c[2] + (float)d[2];
    o0.w = (float)a[3] + (float)b[3] + (float)c[3] + (float)d[3];
    o1.x = (float)a[4] + (float)b[4] + (float)c[4] + (float)d[4];
    o1.y = (float)a[5] + (float)b[5] + (float)c[5] + (float)d[5];
    o1.z = (float)a[6] + (float)b[6] + (float)c[6] + (float)d[6];
    o1.w = (float)a[7] + (float)b[7] + (float)c[7] + (float)d[7];
    out[2 * i]     = o0;
    out[2 * i + 1] = o1;
}

// ---------------- depthwise causal conv (K=4) + silu ----------------
// xz bf16; accumulate in f32; emit bf16 (scan reads bf16 too).
__global__ void k_conv_silu(const bf16_t* __restrict__ xz,
                            const float* __restrict__ conv_w,
                            const float* __restrict__ conv_b,
                            bf16_t* __restrict__ xc_bf) {
    int idx = blockIdx.x * 256 + threadIdx.x;   // over L*ED
    int e = idx & (ED - 1);
    int t = idx >> 11;
    float w0 = conv_w[e * 4 + 0], w1 = conv_w[e * 4 + 1];
    float w2 = conv_w[e * 4 + 2], w3 = conv_w[e * 4 + 3];
    const bf16_t* col = xz + e;
    float acc = conv_b[e];
    if (t >= 3) acc += w0 * (float)col[(size_t)(t - 3) * 4096];
    if (t >= 2) acc += w1 * (float)col[(size_t)(t - 2) * 4096];
    if (t >= 1) acc += w2 * (float)col[(size_t)(t - 1) * 4096];
    acc += w3 * (float)col[(size_t)t * 4096];
    float s = acc / (1.f + __expf(-acc));       // silu
    xc_bf[idx] = (bf16_t)s;
}

// reduce GEMM2 split-K partials -> dBC fp32; also emit dly bf16 (cols 0:64)
__global__ void k_red2(const float* __restrict__ part, float* __restrict__ dBC,
                       bf16_t* __restrict__ dly) {
    int idx = blockIdx.x * 256 + threadIdx.x;   // L*96
    int t = idx / 96, c = idx - t * 96;
    float s = 0.f;
#pragma unroll
    for (int sp = 0; sp < SPLITS; sp++) s += part[(size_t)sp * L * 96 + idx];
    dBC[idx] = s;
    if (c < 64) dly[t * 64 + c] = (bf16_t)s;
}

// ---------------- chunked scan: thread = (chunk, e), 16 n-states in regs ----
// recurrence per (e,n):  v_t = B*v_{t-1} + u_t ;  h_t = a_t*h_{t-1} + v_t
// pass1 computes transition summary (h,v,p,q) per chunk with zero init;
// combine turns summaries into incoming states, written to compact float2 inc;
// pass2 re-runs the recurrence from the true incoming state and emits gated g.
// summ layout: [n][chunk][e] float4 -> coalesced per-instr access everywhere.

__global__ __launch_bounds__(256)
void k_scan_p1(const bf16_t* __restrict__ delta, const bf16_t* __restrict__ xc,
               const float* __restrict__ dBC, const float* __restrict__ A_log,
               float4* __restrict__ summ) {
    const int chunk = blockIdx.x >> 3;                 // 8 blocks per chunk
    const int e = (blockIdx.x & 7) * 256 + threadIdx.x;
    float A[NST];
#pragma unroll
    for (int n = 0; n < NST; n++) A[n] = -__expf(A_log[e * NST + n]);
    float h[NST], v[NST], p[NST], q[NST];
#pragma unroll
    for (int n = 0; n < NST; n++) { h[n] = 0.f; v[n] = 0.f; p[n] = 1.f; q[n] = 0.f; }
    float bp = 1.f;
    const int t0 = chunk * LCH;
    for (int i = 0; i < LCH; i++) {
        int t = t0 + i;                                // block-uniform
        float d   = (float)delta[(size_t)t * ED + e];
        float xcv = (float)xc[(size_t)t * ED + e];
        float du  = d * xcv;
        bp *= BETA;
        const float* Bp = &dBC[t * 96 + 64];           // wave-uniform -> scalar loads
#pragma unroll
        for (int n = 0; n < NST; n++) {
            float a = __expf(d * A[n]);
            v[n] = BETA * v[n] + du * Bp[n];
            h[n] = a * h[n] + v[n];
            p[n] *= a;
            q[n] = a * q[n] + bp;
        }
    }
#pragma unroll
    for (int n = 0; n < NST; n++)
        summ[((size_t)n * NCHUNK + chunk) * ED + e] = make_float4(h[n], v[n], p[n], q[n]);
}

// sequential over chunks; writes incoming state (h,v) to compact inc array
__global__ void k_combine(const float4* __restrict__ summ, float2* __restrict__ inc) {
    int tid = blockIdx.x * 256 + threadIdx.x;   // ED*NST threads; tid = n*ED + e
    int n = tid >> 11, e = tid & (ED - 1);
    float h = 0.f, v = 0.f;
    const float bl = 7.9586611e-8f;             // 0.6^32
#pragma unroll 4
    for (int c = 0; c < NCHUNK; c++) {
        size_t idx = ((size_t)n * NCHUNK + c) * ED + e;
        float4 f = summ[idx];                   // (hL, vL, p, q)
        inc[idx] = make_float2(h, v);           // incoming state for chunk c
        float hn = f.z * h + f.w * v + f.x;
        v = bl * v + f.y;
        h = hn;
    }
}

__global__ __launch_bounds__(256)
void k_scan_p2(const bf16_t* __restrict__ delta, const bf16_t* __restrict__ xc,
               const float* __restrict__ dBC, const float* __restrict__ A_log,
               const float2* __restrict__ inc, const float* __restrict__ Dvec,
               const bf16_t* __restrict__ xz, bf16_t* __restrict__ g) {
    const int chunk = blockIdx.x >> 3;
    const int e = (blockIdx.x & 7) * 256 + threadIdx.x;
    float A[NST];
#pragma unroll
    for (int n = 0; n < NST; n++) A[n] = -__expf(A_log[e * NST + n]);
    float h[NST], v[NST];
#pragma unroll
    for (int n = 0; n < NST; n++) {
        float2 s = inc[((size_t)n * NCHUNK + chunk) * ED + e];
        h[n] = s.x; v[n] = s.y;                 // true incoming state: no p/q needed
    }
    const float De = Dvec[e];
    const int t0 = chunk * LCH;
    for (int i = 0; i < LCH; i++) {
        int t = t0 + i;
        float d   = (float)delta[(size_t)t * ED + e];
        float xcv = (float)xc[(size_t)t * ED + e];
        float du  = d * xcv;
        const float* Bp = &dBC[t * 96 + 64];
        const float* Cp = &dBC[t * 96 + 80];
        float yacc = 0.f;
#pragma unroll
        for (int n = 0; n < NST; n++) {
            float a = __expf(d * A[n]);
            v[n] = BETA * v[n] + du * Bp[n];
            h[n] = a * h[n] + v[n];
            yacc += Cp[n] * h[n];
        }
        // fused gate: g = bf16((y + D*xc) * silu(z)); z from bf16 xz
        float z = (float)xz[(size_t)t * 4096 + ED + e];
        float sz = z / (1.f + __expf(-z));
        g[(size_t)t * ED + e] = (bf16_t)((yacc + De * xcv) * sz);
    }
}

// ---------------- launch ----------------

extern "C" void kernel_launch(void* const* d_in, const int* in_sizes, int n_in,
                              void* d_out, int out_size, void* d_ws, size_t ws_size,
                              hipStream_t stream) {
    const float* x      = (const float*)d_in[0];
    const float* W_in   = (const float*)d_in[1];
    const float* conv_w = (const float*)d_in[2];
    const float* conv_b = (const float*)d_in[3];
    const float* W_x    = (const float*)d_in[4];
    const float* W_dt   = (const float*)d_in[5];
    const float* b_dt   = (const float*)d_in[6];
    const float* A_log  = (const float*)d_in[7];
    const float* Dv     = (const float*)d_in[8];
    const float* W_out  = (const float*)d_in[9];
    float* out = (float*)d_out;

    // workspace layout (bytes); lifetime-based aliasing:
    //  XZ region: xz bf16 (GEMM1..p2, 16MB) then GEMM4 bf16 split-K partials (16MB)
    //  XC region: inc float2 (combine->p2), exactly 16MB
    //  C  region: xc_bf (conv..p2)
    //  DELTA region: delta bf16 (8MB) | g_bf at +8MB (p2..GEMM4)
    //  R1 region: Win_bf | part2 at +16MB | summ alias (33.5MB, after GEMM3)
    constexpr size_t OFF_XZ    = 0;           // 33554432
    constexpr size_t OFF_XC    = 33554432;    // 16777216  inc (float2, 16MB exact)
    constexpr size_t OFF_C     = 50331648;    //  8388608  xc_bf
    constexpr size_t OFF_DELTA = 58720256;    // 16777216  delta bf16 | g_bf at +8MB
    constexpr size_t OFF_R1    = 75497472;    // 33554432
    constexpr size_t OFF_XBF   = 109051904;   //  4194304  x_bf
    constexpr size_t OFF_DBC   = 113246208;   //   786432  dBC (L,96) f32
    constexpr size_t OFF_DLY   = 114032640;   //   262144  delta_r bf16
    constexpr size_t OFF_WX    = 114294784;   //   393216
    constexpr size_t OFF_WDT   = 114688000;   //   262144
    constexpr size_t OFF_WOUT  = 114950144;   //  4194304  Wout_bf (dedicated)
    constexpr size_t WS_NEED   = 119144448;

    if (ws_size < WS_NEED) {   // loud, diagnosable failure
        k_fill<<<(out_size + 255) / 256, 256, 0, stream>>>(out, 1.0e9f, out_size);
        return;
    }

    char* ws = (char*)d_ws;
    bf16_t* xz_bf = (bf16_t*)(ws + OFF_XZ);
    bf16_t* part4 = (bf16_t*)(ws + OFF_XZ);     // alias: xz dead after p2
    float2* inc   = (float2*)(ws + OFF_XC);
    bf16_t* xc_bf = (bf16_t*)(ws + OFF_C);
    bf16_t* delta_bf = (bf16_t*)(ws + OFF_DELTA);
    bf16_t* g_bf  = (bf16_t*)(ws + OFF_DELTA + 8388608);  // delta dead only after p2; separate slot
    bf16_t* Win_bf  = (bf16_t*)(ws + OFF_R1);
    float*  part2   = (float*)(ws + OFF_R1 + 16777216);
    float4* summ    = (float4*)(ws + OFF_R1);   // alias: Win/part2 dead after GEMM3
    bf16_t* x_bf  = (bf16_t*)(ws + OFF_XBF);
    float*  dBC   = (float*)(ws + OFF_DBC);
    bf16_t* dly   = (bf16_t*)(ws + OFF_DLY);
    bf16_t* Wx_bf  = (bf16_t*)(ws + OFF_WX);
    bf16_t* Wdt_bf = (bf16_t*)(ws + OFF_WDT);
    bf16_t* Wout_bf = (bf16_t*)(ws + OFF_WOUT);

    // single merged conversion (fixed wave-uniform segment boundaries)
    k_cvt_all<<<8512, 256, 0, stream>>>(
        (const float4*)x,     (bf16x4*)x_bf,
        (const float4*)W_in,  (bf16x4*)Win_bf,
        (const float4*)W_x,   (bf16x4*)Wx_bf,
        (const float4*)W_dt,  (bf16x4*)Wdt_bf,
        (const float4*)W_out, (bf16x4*)Wout_bf);

    // GEMM1: xz = x @ W_in^T   (M=L, N=4096, K=DM), bf16 output
    {
        dim3 g(4096 / 128, L / 128, 1);
        k_gemm_bt<2, false><<<g, 256, 0, stream>>>(x_bf, Win_bf, (float*)xz_bf, L, 4096, DM, 4096, DM, nullptr);
    }
    k_conv_silu<<<L * ED / 256, 256, 0, stream>>>(xz_bf, conv_w, conv_b, xc_bf);
    // GEMM2 split-K: part2[z] = xc @ W_x^T over k-range z  (M=L, N=96, K=ED)
    {
        dim3 g(1, L / 128, SPLITS);
        k_gemm_bt<0, true><<<g, 256, 0, stream>>>(xc_bf, Wx_bf, part2, L, 96, ED, 96, ED / SPLITS, nullptr);
    }
    k_red2<<<L * 96 / 256, 256, 0, stream>>>(part2, dBC, dly);
    // GEMM3: delta = softplus(dly @ W_dt^T + b_dt)  (M=L, N=ED, K=64), bf16 output
    {
        dim3 g(ED / 128, L / 128, 1);
        k_gemm_bt<1, false><<<g, 256, 0, stream>>>(dly, Wdt_bf, (float*)delta_bf, L, ED, DTR, ED, DTR, b_dt);
    }
    // chunked scan
    k_scan_p1<<<NCHUNK * 8, 256, 0, stream>>>(delta_bf, xc_bf, dBC, A_log, summ);
    k_combine<<<ED * NST / 256, 256, 0, stream>>>(summ, inc);
    k_scan_p2<<<NCHUNK * 8, 256, 0, stream>>>(delta_bf, xc_bf, dBC, A_log, inc, Dv, xz_bf, g_bf);
    // GEMM4 split-K: part4[z] = g @ W_out^T over k-range z  (M=L, N=DM, K=ED), bf16 partials
    {
        dim3 g(DM / 128, L / 128, SPLIT4);
        k_gemm_bt<2, false><<<g, 256, 0, stream>>>(g_bf, Wout_bf, (float*)part4, L, DM, ED, DM, ED / SPLIT4, nullptr);
    }
    k_red4<<<L * DM / 8 / 256, 256, 0, stream>>>((const bf16x8*)part4, (float4*)out);
}